// Round 1
// baseline (3173.846 us; speedup 1.0000x reference)
//
#include <hip/hip_runtime.h>
#include <math.h>

#define HF 129
#define WF 129
#define BDIM 2
#define TOK (BDIM*HF*WF)   /* 33282 */
#define DMOD 128

__device__ __forceinline__ float leaky(float v){ return v > 0.f ? v : 0.01f*v; }

// ---------------- patchify: x*pos_w+pos_b, wrap-pad 2, conv 4x4 stride 2 -> f [T,128] ----------------
__global__ __launch_bounds__(128) void patchify_kernel(
    const float* __restrict__ x, const float* __restrict__ pos_w, const float* __restrict__ pos_b,
    const float* __restrict__ pw, const float* __restrict__ pb, float* __restrict__ f)
{
    __shared__ float xs[48];
    int p = blockIdx.x;
    int b = p / (HF*WF);
    int rem = p - b*HF*WF;
    int oh = rem / WF, ow = rem - oh*WF;
    int tid = threadIdx.x;
    if (tid < 48) {
        int c = tid >> 4, k = tid & 15;
        int kh = k >> 2, kw = k & 3;
        int h = (oh*2 + kh - 2 + 256) & 255;
        int w = (ow*2 + kw - 2 + 256) & 255;
        int xi = ((b*3 + c)*256 + h)*256 + w;
        int pi = (c*256 + h)*256 + w;
        xs[tid] = x[xi]*pos_w[pi] + pos_b[pi];
    }
    __syncthreads();
    int d = tid;
    float acc = pb[d];
    const float* wrow = pw + d*48;
    #pragma unroll
    for (int i = 0; i < 48; ++i) acc += xs[i]*wrow[i];
    f[(size_t)p*DMOD + d] = acc;
}

// ---------------- LayerNorm over 128 channels, one wave per token ----------------
__global__ __launch_bounds__(256) void ln_kernel(const float* __restrict__ in,
    const float* __restrict__ g, const float* __restrict__ bta, float* __restrict__ out)
{
    int lane = threadIdx.x & 63;
    int wv = threadIdx.x >> 6;
    int tok = blockIdx.x*4 + wv;
    if (tok >= TOK) return;
    const float* row = in + (size_t)tok*DMOD;
    float x0 = row[lane], x1 = row[lane+64];
    float s = x0 + x1, ss = x0*x0 + x1*x1;
    #pragma unroll
    for (int m = 1; m < 64; m <<= 1) { s += __shfl_xor(s, m); ss += __shfl_xor(ss, m); }
    float mean = s * (1.f/128.f);
    float var = ss * (1.f/128.f) - mean*mean;
    float inv = rsqrtf(var + 1e-5f);
    float* orow = out + (size_t)tok*DMOD;
    orow[lane]    = (x0-mean)*inv*g[lane]    + bta[lane];
    orow[lane+64] = (x1-mean)*inv*g[lane+64] + bta[lane+64];
}

// ---------------- f32 GEMM: C[M,N] = act(A[M,K] @ W[N,K]^T + bias) (+= if RES) ----------------
// BM=BN=128, BK=32, 256 threads, 8x8 per thread.
template<int ACT, int RES>
__global__ __launch_bounds__(256) void gemm_kernel(
    const float* __restrict__ A, const float* __restrict__ W, const float* __restrict__ bias,
    float* __restrict__ C, int M, int N, int K)
{
    __shared__ float As[128][33];
    __shared__ float Ws[128][33];
    int bm = blockIdx.x * 128, bn = blockIdx.y * 128;
    int tid = threadIdx.x;
    int tx = tid & 15, ty = tid >> 4;
    float acc[8][8] = {};
    for (int k0 = 0; k0 < K; k0 += 32) {
        #pragma unroll
        for (int i = 0; i < 16; ++i) {
            int idx = tid + i*256;
            int r = idx >> 5, c = idx & 31;
            int gm = bm + r;
            As[r][c] = (gm < M) ? A[(size_t)gm*K + k0 + c] : 0.f;
            Ws[r][c] = W[(size_t)(bn + r)*K + k0 + c];
        }
        __syncthreads();
        #pragma unroll
        for (int kk = 0; kk < 32; ++kk) {
            float av[8], bv[8];
            #pragma unroll
            for (int i = 0; i < 8; ++i) av[i] = As[ty + i*16][kk];
            #pragma unroll
            for (int j = 0; j < 8; ++j) bv[j] = Ws[tx + j*16][kk];
            #pragma unroll
            for (int i = 0; i < 8; ++i)
                #pragma unroll
                for (int j = 0; j < 8; ++j) acc[i][j] += av[i]*bv[j];
        }
        __syncthreads();
    }
    #pragma unroll
    for (int i = 0; i < 8; ++i) {
        int m = bm + ty + i*16;
        if (m >= M) continue;
        #pragma unroll
        for (int j = 0; j < 8; ++j) {
            int n = bn + tx + j*16;
            float v = acc[i][j] + bias[n];
            if (ACT == 1) v = leaky(v);
            if (RES) C[(size_t)m*N + n] += v; else C[(size_t)m*N + n] = v;
        }
    }
}

// ---------------- neighborhood attention: one thread per (token, head) ----------------
__global__ __launch_bounds__(256) void attn_kernel(const float* __restrict__ qkv,
    const float* __restrict__ rpb, float* __restrict__ o)
{
    int gid = blockIdx.x*256 + threadIdx.x;
    int tok = gid >> 3;
    if (tok >= TOK) return;
    int head = gid & 7;
    int b = tok / (HF*WF);
    int rem = tok - b*HF*WF;
    int y = rem / WF, x = rem - y*WF;
    const float* qp = qkv + (size_t)tok*384 + head*16;
    float q[16];
    #pragma unroll
    for (int i = 0; i < 16; ++i) q[i] = qp[i]*0.25f;
    float logits[25];
    float mx = -1e30f;
    #pragma unroll
    for (int di = -2; di <= 2; ++di) {
        int ny = y + di; ny += (ny < 0) ? HF : 0; ny -= (ny >= HF) ? HF : 0;
        #pragma unroll
        for (int dj = -2; dj <= 2; ++dj) {
            int nx = x + dj; nx += (nx < 0) ? WF : 0; nx -= (nx >= WF) ? WF : 0;
            size_t nt = (size_t)((b*HF + ny)*WF + nx);
            const float* kp = qkv + nt*384 + 128 + head*16;
            float d = 0.f;
            #pragma unroll
            for (int i = 0; i < 16; ++i) d += q[i]*kp[i];
            d += rpb[head*81 + (di+4)*9 + (dj+4)];
            logits[(di+2)*5 + (dj+2)] = d;
            mx = fmaxf(mx, d);
        }
    }
    float s = 0.f;
    #pragma unroll
    for (int n = 0; n < 25; ++n) { float p = __expf(logits[n]-mx); logits[n] = p; s += p; }
    float invs = 1.f/s;
    float outv[16] = {};
    #pragma unroll
    for (int di = -2; di <= 2; ++di) {
        int ny = y + di; ny += (ny < 0) ? HF : 0; ny -= (ny >= HF) ? HF : 0;
        #pragma unroll
        for (int dj = -2; dj <= 2; ++dj) {
            int nx = x + dj; nx += (nx < 0) ? WF : 0; nx -= (nx >= WF) ? WF : 0;
            size_t nt = (size_t)((b*HF + ny)*WF + nx);
            const float* vp = qkv + nt*384 + 256 + head*16;
            float p = logits[(di+2)*5 + (dj+2)];
            #pragma unroll
            for (int i = 0; i < 16; ++i) outv[i] += p*vp[i];
        }
    }
    float* op = o + (size_t)tok*DMOD + head*16;
    #pragma unroll
    for (int i = 0; i < 16; ++i) op[i] = outv[i]*invs;
}

// ---------------- depatchify (transposed conv stride 2, crop 2) -> y image [B,3,256,256] ----------------
// y[b,c,i,j] = sum over the 2x2 feature pixels {i/2, i/2+1} x {j/2, j/2+1}:
//   weight row (i even ? {2,0} : {3,1}), col (j even ? {2,0} : {3,1})
__global__ __launch_bounds__(256) void depatch_kernel(const float* __restrict__ f,
    const float* __restrict__ dw, const float* __restrict__ db, float* __restrict__ yimg)
{
    int idx = blockIdx.x*256 + threadIdx.x;
    int b = idx >> 16;
    int pix = idx & 65535;
    int i = pix >> 8, j = pix & 255;
    int fh0 = i >> 1, fw0 = j >> 1;
    int wr0 = 2 + (i & 1), wr1 = (i & 1);
    int wc0 = 2 + (j & 1), wc1 = (j & 1);
    float acc0 = db[0], acc1 = db[1], acc2 = db[2];
    #pragma unroll
    for (int a = 0; a < 2; ++a) {
        int fh = fh0 + a;
        int wr = a ? wr1 : wr0;
        #pragma unroll
        for (int bb = 0; bb < 2; ++bb) {
            int fw = fw0 + bb;
            int wc = bb ? wc1 : wc0;
            const float* fp = f + (size_t)((b*HF + fh)*WF + fw)*DMOD;
            const float* wb = dw + wr*4 + wc;
            #pragma unroll 4
            for (int d = 0; d < 128; ++d) {
                float v = fp[d];
                acc0 += v * wb[d*48];
                acc1 += v * wb[d*48 + 16];
                acc2 += v * wb[d*48 + 32];
            }
        }
    }
    size_t base = ((size_t)b*3*256 + i)*256 + j;
    yimg[base]            = acc0;
    yimg[base + 65536]    = acc1;
    yimg[base + 2*65536]  = acc2;
}

// ---------------- residual conv tail: out = y + conv1x1(leaky(conv5x5_wrap(y))) ----------------
__global__ __launch_bounds__(256) void res_kernel(const float* __restrict__ y,
    const float* __restrict__ w1, const float* __restrict__ b1,
    const float* __restrict__ w2, const float* __restrict__ b2, float* __restrict__ out)
{
    int idx = blockIdx.x*256 + threadIdx.x;
    int b = idx >> 16;
    int pix = idx & 65535;
    int i = pix >> 8, j = pix & 255;
    float yv[3][5][5];
    #pragma unroll
    for (int c = 0; c < 3; ++c) {
        #pragma unroll
        for (int u = 0; u < 5; ++u) {
            int ii = (i + u - 2 + 256) & 255;
            #pragma unroll
            for (int v = 0; v < 5; ++v) {
                int jj = (j + v - 2 + 256) & 255;
                yv[c][u][v] = y[((size_t)(b*3 + c)*256 + ii)*256 + jj];
            }
        }
    }
    float r1[12];
    #pragma unroll
    for (int rc = 0; rc < 12; ++rc) {
        float a = b1[rc];
        #pragma unroll
        for (int c = 0; c < 3; ++c)
            #pragma unroll
            for (int u = 0; u < 5; ++u)
                #pragma unroll
                for (int v = 0; v < 5; ++v)
                    a += yv[c][u][v] * w1[rc*75 + c*25 + u*5 + v];
        r1[rc] = leaky(a);
    }
    #pragma unroll
    for (int c = 0; c < 3; ++c) {
        float a = b2[c];
        #pragma unroll
        for (int rc = 0; rc < 12; ++rc) a += r1[rc]*w2[c*12 + rc];
        out[((size_t)(b*3 + c)*256 + i)*256 + j] = yv[c][2][2] + a;
    }
}

extern "C" void kernel_launch(void* const* d_in, const int* in_sizes, int n_in,
                              void* d_out, int out_size, void* d_ws, size_t ws_size,
                              hipStream_t stream)
{
    const float* x      = (const float*)d_in[0];
    const float* pos_w  = (const float*)d_in[1];
    const float* pos_b  = (const float*)d_in[2];
    const float* patch_w= (const float*)d_in[3];
    const float* patch_b= (const float*)d_in[4];
    const float* ln1_g  = (const float*)d_in[5];
    const float* ln1_b  = (const float*)d_in[6];
    const float* qkv_w  = (const float*)d_in[7];
    const float* qkv_b  = (const float*)d_in[8];
    const float* rpb    = (const float*)d_in[9];
    const float* proj_w = (const float*)d_in[10];
    const float* proj_b = (const float*)d_in[11];
    const float* ln2_g  = (const float*)d_in[12];
    const float* ln2_b  = (const float*)d_in[13];
    const float* fc1_w  = (const float*)d_in[14];
    const float* fc1_b  = (const float*)d_in[15];
    const float* fc2_w  = (const float*)d_in[16];
    const float* fc2_b  = (const float*)d_in[17];
    const float* dep_w  = (const float*)d_in[18];
    const float* dep_b  = (const float*)d_in[19];
    const float* rc1_w  = (const float*)d_in[20];
    const float* rc1_b  = (const float*)d_in[21];
    const float* rc2_w  = (const float*)d_in[22];
    const float* rc2_b  = (const float*)d_in[23];

    const size_t SZ = (size_t)TOK * 128;
    float* ws  = (float*)d_ws;
    float* f   = ws;            // [T,128] residual stream
    float* yln = ws + SZ;       // [T,128] LN output / attention output (shared)
    float* big = ws + 2*SZ;     // [T,512] qkv (uses 384) / fc1 hidden (shared)
    float* yimg= ws + 6*SZ;     // [B,3,256,256]

    patchify_kernel<<<TOK, 128, 0, stream>>>(x, pos_w, pos_b, patch_w, patch_b, f);

    const int GM = (TOK + 127)/128;   // 261
    for (int l = 0; l < 3; ++l) {
        ln_kernel<<<(TOK+3)/4, 256, 0, stream>>>(f, ln1_g + l*128, ln1_b + l*128, yln);
        gemm_kernel<0,0><<<dim3(GM,3), 256, 0, stream>>>(yln, qkv_w + (size_t)l*384*128, qkv_b + l*384, big, TOK, 384, 128);
        attn_kernel<<<(TOK*8 + 255)/256, 256, 0, stream>>>(big, rpb + l*8*81, yln);
        gemm_kernel<0,1><<<dim3(GM,1), 256, 0, stream>>>(yln, proj_w + (size_t)l*128*128, proj_b + l*128, f, TOK, 128, 128);
        ln_kernel<<<(TOK+3)/4, 256, 0, stream>>>(f, ln2_g + l*128, ln2_b + l*128, yln);
        gemm_kernel<1,0><<<dim3(GM,4), 256, 0, stream>>>(yln, fc1_w + (size_t)l*512*128, fc1_b + l*512, big, TOK, 512, 128);
        gemm_kernel<0,1><<<dim3(GM,1), 256, 0, stream>>>(big, fc2_w + (size_t)l*128*512, fc2_b + l*128, f, TOK, 128, 512);
    }

    depatch_kernel<<<512, 256, 0, stream>>>(f, dep_w, dep_b, yimg);
    res_kernel<<<512, 256, 0, stream>>>(yimg, rc1_w, rc1_b, rc2_w, rc2_b, (float*)d_out);
}

// Round 2
// 469.467 us; speedup vs baseline: 6.7605x; 6.7605x over previous
//
#include <hip/hip_runtime.h>
#include <hip/hip_bf16.h>
#include <math.h>

#define HF 129
#define WF 129
#define BDIM 2
#define TOK (BDIM*HF*WF)   /* 33282 */
#define DMOD 128

typedef __attribute__((ext_vector_type(8))) short short8;
typedef __attribute__((ext_vector_type(8))) unsigned short ushort8;
typedef __attribute__((ext_vector_type(4))) float f32x4;

__device__ __forceinline__ float leaky(float v){ return v > 0.f ? v : 0.01f*v; }
__device__ __forceinline__ float bf2f(unsigned short u){ return __uint_as_float(((unsigned int)u) << 16); }

// ---------------- f32 -> bf16 conversion (weights) ----------------
__global__ __launch_bounds__(256) void f2b_kernel(const float* __restrict__ in,
    __hip_bfloat16* __restrict__ out, int n)
{
    int idx = (blockIdx.x*256 + threadIdx.x)*4;
    if (idx >= n) return;
    float4 v = *(const float4*)(in + idx);
    out[idx]   = __float2bfloat16(v.x);
    out[idx+1] = __float2bfloat16(v.y);
    out[idx+2] = __float2bfloat16(v.z);
    out[idx+3] = __float2bfloat16(v.w);
}

// ---------------- patchify: x*pos_w+pos_b, wrap-pad 2, conv 4x4 stride 2 -> f [T,128] f32 ----------------
__global__ __launch_bounds__(128) void patchify_kernel(
    const float* __restrict__ x, const float* __restrict__ pos_w, const float* __restrict__ pos_b,
    const float* __restrict__ pw, const float* __restrict__ pb, float* __restrict__ f)
{
    __shared__ float xs[48];
    int p = blockIdx.x;
    int b = p / (HF*WF);
    int rem = p - b*HF*WF;
    int oh = rem / WF, ow = rem - oh*WF;
    int tid = threadIdx.x;
    if (tid < 48) {
        int c = tid >> 4, k = tid & 15;
        int kh = k >> 2, kw = k & 3;
        int h = (oh*2 + kh - 2 + 256) & 255;
        int w = (ow*2 + kw - 2 + 256) & 255;
        int xi = ((b*3 + c)*256 + h)*256 + w;
        int pi = (c*256 + h)*256 + w;
        xs[tid] = x[xi]*pos_w[pi] + pos_b[pi];
    }
    __syncthreads();
    int d = tid;
    float acc = pb[d];
    const float* wrow = pw + d*48;
    #pragma unroll
    for (int i = 0; i < 48; ++i) acc += xs[i]*wrow[i];
    f[(size_t)p*DMOD + d] = acc;
}

// ---------------- LayerNorm over 128 channels, one wave per token, f32 in -> bf16 out ----------------
__global__ __launch_bounds__(256) void ln_kernel(const float* __restrict__ in,
    const float* __restrict__ g, const float* __restrict__ bta, __hip_bfloat16* __restrict__ out)
{
    int lane = threadIdx.x & 63;
    int wv = threadIdx.x >> 6;
    int tok = blockIdx.x*4 + wv;
    if (tok >= TOK) return;
    const float* row = in + (size_t)tok*DMOD;
    float x0 = row[lane], x1 = row[lane+64];
    float s = x0 + x1, ss = x0*x0 + x1*x1;
    #pragma unroll
    for (int m = 1; m < 64; m <<= 1) { s += __shfl_xor(s, m); ss += __shfl_xor(ss, m); }
    float mean = s * (1.f/128.f);
    float var = ss * (1.f/128.f) - mean*mean;
    float inv = rsqrtf(var + 1e-5f);
    __hip_bfloat16* orow = out + (size_t)tok*DMOD;
    orow[lane]    = __float2bfloat16((x0-mean)*inv*g[lane]    + bta[lane]);
    orow[lane+64] = __float2bfloat16((x1-mean)*inv*g[lane+64] + bta[lane+64]);
}

// ---------------- bf16 MFMA GEMM: C[M,N] = act(A[M,K] @ W[N,K]^T + bias) ----------------
// BM=BN=BK=64, 256 threads = 4 waves in 2x2, each wave 32x32 output (2x2 16x16 frags).
// LDS XOR-swizzle: byte ^= (row&7)<<4 -> conflict-free ds_write_b128 / ds_read_b128.
template<int ACT, int RES>
__global__ __launch_bounds__(256) void mgemm_kernel(
    const __hip_bfloat16* __restrict__ A, const __hip_bfloat16* __restrict__ W,
    const float* __restrict__ bias, __hip_bfloat16* __restrict__ Cbf,
    float* __restrict__ Cres, int M, int N, int K)
{
    __shared__ __align__(16) char As[64*128];
    __shared__ __align__(16) char Ws[64*128];
    int tid = threadIdx.x;
    int bm = blockIdx.x*64, bn = blockIdx.y*64;
    int lane = tid & 63, wid = tid >> 6;
    int wm = (wid >> 1)*32, wn = (wid & 1)*32;
    int lrow = lane & 15, lq = lane >> 4;
    // staging: thread t loads rows (t>>3) and (t>>3)+32, col-group t&7 (8 bf16 = 16B)
    int srow = tid >> 3, scg = tid & 7;
    int wo0 = ((srow     )*128 + scg*16) ^ ((srow&7)<<4);
    int wo1 = ((srow + 32)*128 + scg*16) ^ ((srow&7)<<4);
    // fragment read bases (byte offsets, pre-XOR)
    int swz = (lrow & 7) << 4;
    int baseA0 = (wm + lrow     )*128 + lq*16;
    int baseA1 = (wm + 16 + lrow)*128 + lq*16;
    int baseB0 = (wn + lrow     )*128 + lq*16;
    int baseB1 = (wn + 16 + lrow)*128 + lq*16;

    f32x4 acc[2][2] = {};
    bool v0 = (bm + srow) < M, v1 = (bm + srow + 32) < M;
    const __hip_bfloat16* a0p = A + (size_t)(bm + srow)*K + scg*8;
    const __hip_bfloat16* a1p = A + (size_t)(bm + srow + 32)*K + scg*8;
    const __hip_bfloat16* w0p = W + (size_t)(bn + srow)*K + scg*8;
    const __hip_bfloat16* w1p = W + (size_t)(bn + srow + 32)*K + scg*8;

    for (int k0 = 0; k0 < K; k0 += 64) {
        int4 va0 = {}, va1 = {};
        if (v0) va0 = *(const int4*)(a0p + k0);
        if (v1) va1 = *(const int4*)(a1p + k0);
        int4 vw0 = *(const int4*)(w0p + k0);
        int4 vw1 = *(const int4*)(w1p + k0);
        __syncthreads();   // protect previous-iteration reads
        *(int4*)(As + wo0) = va0;
        *(int4*)(As + wo1) = va1;
        *(int4*)(Ws + wo0) = vw0;
        *(int4*)(Ws + wo1) = vw1;
        __syncthreads();
        #pragma unroll
        for (int ks = 0; ks < 2; ++ks) {
            int kb = ks*64;
            short8 a0 = *(const short8*)(As + ((baseA0 + kb) ^ swz));
            short8 a1 = *(const short8*)(As + ((baseA1 + kb) ^ swz));
            short8 b0 = *(const short8*)(Ws + ((baseB0 + kb) ^ swz));
            short8 b1 = *(const short8*)(Ws + ((baseB1 + kb) ^ swz));
            acc[0][0] = __builtin_amdgcn_mfma_f32_16x16x32_bf16(a0, b0, acc[0][0], 0, 0, 0);
            acc[0][1] = __builtin_amdgcn_mfma_f32_16x16x32_bf16(a0, b1, acc[0][1], 0, 0, 0);
            acc[1][0] = __builtin_amdgcn_mfma_f32_16x16x32_bf16(a1, b0, acc[1][0], 0, 0, 0);
            acc[1][1] = __builtin_amdgcn_mfma_f32_16x16x32_bf16(a1, b1, acc[1][1], 0, 0, 0);
        }
    }
    // epilogue: C/D layout col=lane&15, row=(lane>>4)*4+reg
    float bv0 = bias[bn + wn + lrow];
    float bv1 = bias[bn + wn + 16 + lrow];
    #pragma unroll
    for (int mi = 0; mi < 2; ++mi) {
        #pragma unroll
        for (int r = 0; r < 4; ++r) {
            int row = bm + wm + mi*16 + lq*4 + r;
            if (row >= M) continue;
            #pragma unroll
            for (int ni = 0; ni < 2; ++ni) {
                float v = acc[mi][ni][r] + (ni ? bv1 : bv0);
                if (ACT == 1) v = leaky(v);
                int col = bn + wn + ni*16 + lrow;
                if (RES) Cres[(size_t)row*N + col] += v;
                else     Cbf[(size_t)row*N + col] = __float2bfloat16(v);
            }
        }
    }
}

// ---------------- neighborhood attention (bf16 in/out): one thread per (token, head) ----------------
__global__ __launch_bounds__(256) void attn_kernel(const __hip_bfloat16* __restrict__ qkv,
    const float* __restrict__ rpb, __hip_bfloat16* __restrict__ o)
{
    int gid = blockIdx.x*256 + threadIdx.x;
    int tok = gid >> 3;
    if (tok >= TOK) return;
    int head = gid & 7;
    int b = tok / (HF*WF);
    int rem = tok - b*HF*WF;
    int y = rem / WF, x = rem - y*WF;
    const ushort8* qp = (const ushort8*)(qkv + (size_t)tok*384 + head*16);
    float q[16];
    {
        ushort8 u0 = qp[0], u1 = qp[1];
        #pragma unroll
        for (int i = 0; i < 8; ++i) { q[i] = bf2f(u0[i])*0.25f; q[i+8] = bf2f(u1[i])*0.25f; }
    }
    float logits[25];
    float mx = -1e30f;
    #pragma unroll
    for (int di = -2; di <= 2; ++di) {
        int ny = y + di; ny += (ny < 0) ? HF : 0; ny -= (ny >= HF) ? HF : 0;
        #pragma unroll
        for (int dj = -2; dj <= 2; ++dj) {
            int nx = x + dj; nx += (nx < 0) ? WF : 0; nx -= (nx >= WF) ? WF : 0;
            size_t nt = (size_t)((b*HF + ny)*WF + nx);
            const ushort8* kp = (const ushort8*)(qkv + nt*384 + 128 + head*16);
            ushort8 k0 = kp[0], k1 = kp[1];
            float d = 0.f;
            #pragma unroll
            for (int i = 0; i < 8; ++i) d += q[i]*bf2f(k0[i]) + q[i+8]*bf2f(k1[i]);
            d += rpb[head*81 + (di+4)*9 + (dj+4)];
            logits[(di+2)*5 + (dj+2)] = d;
            mx = fmaxf(mx, d);
        }
    }
    float s = 0.f;
    #pragma unroll
    for (int n = 0; n < 25; ++n) { float p = __expf(logits[n]-mx); logits[n] = p; s += p; }
    float invs = 1.f/s;
    float outv[16] = {};
    #pragma unroll
    for (int di = -2; di <= 2; ++di) {
        int ny = y + di; ny += (ny < 0) ? HF : 0; ny -= (ny >= HF) ? HF : 0;
        #pragma unroll
        for (int dj = -2; dj <= 2; ++dj) {
            int nx = x + dj; nx += (nx < 0) ? WF : 0; nx -= (nx >= WF) ? WF : 0;
            size_t nt = (size_t)((b*HF + ny)*WF + nx);
            const ushort8* vp = (const ushort8*)(qkv + nt*384 + 256 + head*16);
            ushort8 v0 = vp[0], v1 = vp[1];
            float p = logits[(di+2)*5 + (dj+2)];
            #pragma unroll
            for (int i = 0; i < 8; ++i) { outv[i] += p*bf2f(v0[i]); outv[i+8] += p*bf2f(v1[i]); }
        }
    }
    __hip_bfloat16* op = o + (size_t)tok*DMOD + head*16;
    #pragma unroll
    for (int i = 0; i < 16; ++i) op[i] = __float2bfloat16(outv[i]*invs);
}

// ---------------- depatchify (transposed conv stride 2, crop 2) -> y image [B,3,256,256] f32 ----------------
__global__ __launch_bounds__(256) void depatch_kernel(const float* __restrict__ f,
    const float* __restrict__ dw, const float* __restrict__ db, float* __restrict__ yimg)
{
    int idx = blockIdx.x*256 + threadIdx.x;
    int b = idx >> 16;
    int pix = idx & 65535;
    int i = pix >> 8, j = pix & 255;
    int fh0 = i >> 1, fw0 = j >> 1;
    int wr0 = 2 + (i & 1), wr1 = (i & 1);
    int wc0 = 2 + (j & 1), wc1 = (j & 1);
    float acc0 = db[0], acc1 = db[1], acc2 = db[2];
    #pragma unroll
    for (int a = 0; a < 2; ++a) {
        int fh = fh0 + a;
        int wr = a ? wr1 : wr0;
        #pragma unroll
        for (int bb = 0; bb < 2; ++bb) {
            int fw = fw0 + bb;
            int wc = bb ? wc1 : wc0;
            const float* fp = f + (size_t)((b*HF + fh)*WF + fw)*DMOD;
            const float* wb = dw + wr*4 + wc;
            #pragma unroll 4
            for (int d = 0; d < 128; ++d) {
                float v = fp[d];
                acc0 += v * wb[d*48];
                acc1 += v * wb[d*48 + 16];
                acc2 += v * wb[d*48 + 32];
            }
        }
    }
    size_t base = ((size_t)b*3*256 + i)*256 + j;
    yimg[base]            = acc0;
    yimg[base + 65536]    = acc1;
    yimg[base + 2*65536]  = acc2;
}

// ---------------- residual conv tail: out = y + conv1x1(leaky(conv5x5_wrap(y))) ----------------
__global__ __launch_bounds__(256) void res_kernel(const float* __restrict__ y,
    const float* __restrict__ w1, const float* __restrict__ b1,
    const float* __restrict__ w2, const float* __restrict__ b2, float* __restrict__ out)
{
    int idx = blockIdx.x*256 + threadIdx.x;
    int b = idx >> 16;
    int pix = idx & 65535;
    int i = pix >> 8, j = pix & 255;
    float yv[3][5][5];
    #pragma unroll
    for (int c = 0; c < 3; ++c) {
        #pragma unroll
        for (int u = 0; u < 5; ++u) {
            int ii = (i + u - 2 + 256) & 255;
            #pragma unroll
            for (int v = 0; v < 5; ++v) {
                int jj = (j + v - 2 + 256) & 255;
                yv[c][u][v] = y[((size_t)(b*3 + c)*256 + ii)*256 + jj];
            }
        }
    }
    float r1[12];
    #pragma unroll
    for (int rc = 0; rc < 12; ++rc) {
        float a = b1[rc];
        #pragma unroll
        for (int c = 0; c < 3; ++c)
            #pragma unroll
            for (int u = 0; u < 5; ++u)
                #pragma unroll
                for (int v = 0; v < 5; ++v)
                    a += yv[c][u][v] * w1[rc*75 + c*25 + u*5 + v];
        r1[rc] = leaky(a);
    }
    #pragma unroll
    for (int c = 0; c < 3; ++c) {
        float a = b2[c];
        #pragma unroll
        for (int rc = 0; rc < 12; ++rc) a += r1[rc]*w2[c*12 + rc];
        out[((size_t)(b*3 + c)*256 + i)*256 + j] = yv[c][2][2] + a;
    }
}

extern "C" void kernel_launch(void* const* d_in, const int* in_sizes, int n_in,
                              void* d_out, int out_size, void* d_ws, size_t ws_size,
                              hipStream_t stream)
{
    const float* x      = (const float*)d_in[0];
    const float* pos_w  = (const float*)d_in[1];
    const float* pos_b  = (const float*)d_in[2];
    const float* patch_w= (const float*)d_in[3];
    const float* patch_b= (const float*)d_in[4];
    const float* ln1_g  = (const float*)d_in[5];
    const float* ln1_b  = (const float*)d_in[6];
    const float* qkv_w  = (const float*)d_in[7];
    const float* qkv_b  = (const float*)d_in[8];
    const float* rpb    = (const float*)d_in[9];
    const float* proj_w = (const float*)d_in[10];
    const float* proj_b = (const float*)d_in[11];
    const float* ln2_g  = (const float*)d_in[12];
    const float* ln2_b  = (const float*)d_in[13];
    const float* fc1_w  = (const float*)d_in[14];
    const float* fc1_b  = (const float*)d_in[15];
    const float* fc2_w  = (const float*)d_in[16];
    const float* fc2_b  = (const float*)d_in[17];
    const float* dep_w  = (const float*)d_in[18];
    const float* dep_b  = (const float*)d_in[19];
    const float* rc1_w  = (const float*)d_in[20];
    const float* rc1_b  = (const float*)d_in[21];
    const float* rc2_w  = (const float*)d_in[22];
    const float* rc2_b  = (const float*)d_in[23];

    const size_t SZ = (size_t)TOK * 128;
    char* w = (char*)d_ws;
    float* f            = (float*)w;            w += SZ*4;
    __hip_bfloat16* yln = (__hip_bfloat16*)w;   w += SZ*2;          // LN out / attn out (shared)
    __hip_bfloat16* qkvb= (__hip_bfloat16*)w;   w += (size_t)TOK*384*2;
    __hip_bfloat16* hb  = (__hip_bfloat16*)w;   w += (size_t)TOK*512*2;
    float* yimg         = (float*)w;            w += (size_t)BDIM*3*65536*4;
    __hip_bfloat16* wq  = (__hip_bfloat16*)w;   w += (size_t)3*384*128*2;
    __hip_bfloat16* wp  = (__hip_bfloat16*)w;   w += (size_t)3*128*128*2;
    __hip_bfloat16* w1  = (__hip_bfloat16*)w;   w += (size_t)3*512*128*2;
    __hip_bfloat16* w2  = (__hip_bfloat16*)w;   w += (size_t)3*128*512*2;

    // weight conversion f32 -> bf16
    f2b_kernel<<<(3*384*128/4 + 255)/256, 256, 0, stream>>>(qkv_w, wq, 3*384*128);
    f2b_kernel<<<(3*128*128/4 + 255)/256, 256, 0, stream>>>(proj_w, wp, 3*128*128);
    f2b_kernel<<<(3*512*128/4 + 255)/256, 256, 0, stream>>>(fc1_w, w1, 3*512*128);
    f2b_kernel<<<(3*128*512/4 + 255)/256, 256, 0, stream>>>(fc2_w, w2, 3*128*512);

    patchify_kernel<<<TOK, 128, 0, stream>>>(x, pos_w, pos_b, patch_w, patch_b, f);

    const int GM = (TOK + 63)/64;   // 521
    for (int l = 0; l < 3; ++l) {
        ln_kernel<<<(TOK+3)/4, 256, 0, stream>>>(f, ln1_g + l*128, ln1_b + l*128, yln);
        mgemm_kernel<0,0><<<dim3(GM,6), 256, 0, stream>>>(yln, wq + (size_t)l*384*128,
            qkv_b + l*384, qkvb, nullptr, TOK, 384, 128);
        attn_kernel<<<(TOK*8 + 255)/256, 256, 0, stream>>>(qkvb, rpb + l*8*81, yln);
        mgemm_kernel<0,1><<<dim3(GM,2), 256, 0, stream>>>(yln, wp + (size_t)l*128*128,
            proj_b + l*128, nullptr, f, TOK, 128, 128);
        ln_kernel<<<(TOK+3)/4, 256, 0, stream>>>(f, ln2_g + l*128, ln2_b + l*128, yln);
        mgemm_kernel<1,0><<<dim3(GM,8), 256, 0, stream>>>(yln, w1 + (size_t)l*512*128,
            fc1_b + l*512, hb, nullptr, TOK, 512, 128);
        mgemm_kernel<0,1><<<dim3(GM,2), 256, 0, stream>>>(hb, w2 + (size_t)l*128*512,
            fc2_b + l*128, nullptr, f, TOK, 128, 512);
    }

    depatch_kernel<<<512, 256, 0, stream>>>(f, dep_w, dep_b, yimg);
    res_kernel<<<512, 256, 0, stream>>>(yimg, rc1_w, rc1_b, rc2_w, rc2_b, (float*)d_out);
}

// Round 3
// 392.915 us; speedup vs baseline: 8.0777x; 1.1948x over previous
//
#include <hip/hip_runtime.h>
#include <hip/hip_bf16.h>
#include <math.h>

#define HF 129
#define WF 129
#define BDIM 2
#define TOK (BDIM*HF*WF)   /* 33282 */
#define DMOD 128

typedef __attribute__((ext_vector_type(8))) short short8;
typedef __attribute__((ext_vector_type(8))) unsigned short ushort8;
typedef __attribute__((ext_vector_type(4))) float f32x4;

__device__ __forceinline__ float leaky(float v){ return v > 0.f ? v : 0.01f*v; }
__device__ __forceinline__ float bf2f(unsigned short u){ return __uint_as_float(((unsigned int)u) << 16); }
__device__ __forceinline__ unsigned short f2bf(float f){
    unsigned int u = __float_as_uint(f);
    unsigned int r = (u + 0x7fff + ((u >> 16) & 1)) >> 16;
    return (unsigned short)r;
}

// ---------------- one-shot weight prep: f32->bf16 (+ pad / transpose for conv weights) ----------------
#define NQ 147456
#define NPJ 49152
#define N1 196608
#define N2 196608
#define NPAT 8192
#define NDEP 8192
__global__ __launch_bounds__(256) void prep_weights(
    const float* __restrict__ qkv_w, const float* __restrict__ proj_w,
    const float* __restrict__ fc1_w, const float* __restrict__ fc2_w,
    const float* __restrict__ patch_w, const float* __restrict__ dep_w,
    __hip_bfloat16* __restrict__ wq, __hip_bfloat16* __restrict__ wp,
    __hip_bfloat16* __restrict__ w1, __hip_bfloat16* __restrict__ w2,
    __hip_bfloat16* __restrict__ wpat, __hip_bfloat16* __restrict__ wdep,
    float* __restrict__ zero64)
{
    int off = blockIdx.x*256 + threadIdx.x;
    if (off < NQ) { wq[off] = __float2bfloat16(qkv_w[off]); return; } off -= NQ;
    if (off < NPJ){ wp[off] = __float2bfloat16(proj_w[off]); return; } off -= NPJ;
    if (off < N1) { w1[off] = __float2bfloat16(fc1_w[off]); return; } off -= N1;
    if (off < N2) { w2[off] = __float2bfloat16(fc2_w[off]); return; } off -= N2;
    if (off < NPAT){ int r = off>>6, e = off&63;
        wpat[off] = __float2bfloat16(e < 48 ? patch_w[r*48 + e] : 0.f); return; } off -= NPAT;
    if (off < NDEP){ int e = off>>7, d = off&127;
        wdep[off] = __float2bfloat16(e < 48 ? dep_w[d*48 + e] : 0.f); return; } off -= NDEP;
    if (off < 64) zero64[off] = 0.f;
}

// ---------------- im2col for patchify: x*pos_w+pos_b, wrap, 4x4/stride2 -> [T,64] bf16 (48 used) ----------------
__global__ __launch_bounds__(256) void im2col_kernel(
    const float* __restrict__ x, const float* __restrict__ pos_w, const float* __restrict__ pos_b,
    __hip_bfloat16* __restrict__ G)
{
    __shared__ float xs[12][260];   // 12 = 3ch x 4 rows; 260 stride: 16B-aligned, bank-spread
    int blk = blockIdx.x;           // b*HF + oh
    int b = blk / HF, oh = blk - b*HF;
    int tid = threadIdx.x;
    #pragma unroll
    for (int it = 0; it < 3; ++it) {
        int p = it*4 + (tid >> 6);
        int c = p >> 2, r = p & 3;
        int h = (oh*2 + r - 2 + 256) & 255;
        int w4 = (tid & 63) * 4;
        float4 xv  = *(const float4*)(x     + ((size_t)(b*3 + c)*256 + h)*256 + w4);
        float4 pwv = *(const float4*)(pos_w + ((size_t)c*256 + h)*256 + w4);
        float4 pbv = *(const float4*)(pos_b + ((size_t)c*256 + h)*256 + w4);
        float4 o; o.x = xv.x*pwv.x + pbv.x; o.y = xv.y*pwv.y + pbv.y;
        o.z = xv.z*pwv.z + pbv.z; o.w = xv.w*pwv.w + pbv.w;
        *(float4*)&xs[p][w4] = o;
    }
    __syncthreads();
    int e = tid & 63, og = tid >> 6;
    int c = e >> 4, k = e & 15, kh = k >> 2, kw = k & 3;
    int p = c*4 + kh;
    unsigned short* Grow = (unsigned short*)G + (size_t)blk*WF*64;
    for (int ow = og; ow < WF; ow += 4) {
        unsigned short v = 0;
        if (e < 48) {
            int col = (ow*2 + kw - 2 + 256) & 255;
            v = f2bf(xs[p][col]);
        }
        Grow[ow*64 + e] = v;
    }
}

// ---------------- LayerNorm over 128 channels, one wave per token, f32 in -> bf16 out ----------------
__global__ __launch_bounds__(256) void ln_kernel(const float* __restrict__ in,
    const float* __restrict__ g, const float* __restrict__ bta, __hip_bfloat16* __restrict__ out)
{
    int lane = threadIdx.x & 63;
    int wv = threadIdx.x >> 6;
    int tok = blockIdx.x*4 + wv;
    if (tok >= TOK) return;
    const float* row = in + (size_t)tok*DMOD;
    float x0 = row[lane], x1 = row[lane+64];
    float s = x0 + x1, ss = x0*x0 + x1*x1;
    #pragma unroll
    for (int m = 1; m < 64; m <<= 1) { s += __shfl_xor(s, m); ss += __shfl_xor(ss, m); }
    float mean = s * (1.f/128.f);
    float var = ss * (1.f/128.f) - mean*mean;
    float inv = rsqrtf(var + 1e-5f);
    __hip_bfloat16* orow = out + (size_t)tok*DMOD;
    orow[lane]    = __float2bfloat16((x0-mean)*inv*g[lane]    + bta[lane]);
    orow[lane+64] = __float2bfloat16((x1-mean)*inv*g[lane+64] + bta[lane+64]);
}

// ---------------- bf16 MFMA GEMM: C[M,N] = act(A[M,K] @ W[N,K]^T + bias) ----------------
// BM=BN=BK=64, 256 threads = 4 waves in 2x2, each wave 32x32 output (2x2 16x16 frags).
// LDS XOR-swizzle: byte ^= (row&7)<<4 -> conflict-free ds_write_b128 / ds_read_b128.
// A32: A is f32, packed to bf16 in registers during staging.
// OUTF: write f32 output (Cres = v), else bf16 (Cbf). RES: Cres += v.
template<int ACT, int RES, int OUTF, int A32>
__global__ __launch_bounds__(256) void mgemm_kernel(
    const void* __restrict__ Av, const __hip_bfloat16* __restrict__ W,
    const float* __restrict__ bias, __hip_bfloat16* __restrict__ Cbf,
    float* __restrict__ Cres, int M, int N, int K)
{
    __shared__ __align__(16) char As[64*128];
    __shared__ __align__(16) char Ws[64*128];
    int tid = threadIdx.x;
    int bm = blockIdx.x*64, bn = blockIdx.y*64;
    int lane = tid & 63, wid = tid >> 6;
    int wm = (wid >> 1)*32, wn = (wid & 1)*32;
    int lrow = lane & 15, lq = lane >> 4;
    int srow = tid >> 3, scg = tid & 7;
    int wo0 = ((srow     )*128 + scg*16) ^ ((srow&7)<<4);
    int wo1 = ((srow + 32)*128 + scg*16) ^ ((srow&7)<<4);
    int swz = (lrow & 7) << 4;
    int baseA0 = (wm + lrow     )*128 + lq*16;
    int baseA1 = (wm + 16 + lrow)*128 + lq*16;
    int baseB0 = (wn + lrow     )*128 + lq*16;
    int baseB1 = (wn + 16 + lrow)*128 + lq*16;

    f32x4 acc[2][2] = {};
    bool v0 = (bm + srow) < M, v1 = (bm + srow + 32) < M;
    const __hip_bfloat16* a0p = (const __hip_bfloat16*)Av + (size_t)(bm + srow)*K + scg*8;
    const __hip_bfloat16* a1p = (const __hip_bfloat16*)Av + (size_t)(bm + srow + 32)*K + scg*8;
    const float* a0pf = (const float*)Av + (size_t)(bm + srow)*K + scg*8;
    const float* a1pf = (const float*)Av + (size_t)(bm + srow + 32)*K + scg*8;
    const __hip_bfloat16* w0p = W + (size_t)(bn + srow)*K + scg*8;
    const __hip_bfloat16* w1p = W + (size_t)(bn + srow + 32)*K + scg*8;

    for (int k0 = 0; k0 < K; k0 += 64) {
        int4 va0 = {}, va1 = {};
        if (A32) {
            if (v0) {
                float4 p0 = *(const float4*)(a0pf + k0);
                float4 p1 = *(const float4*)(a0pf + k0 + 4);
                va0.x = f2bf(p0.x) | (f2bf(p0.y) << 16); va0.y = f2bf(p0.z) | (f2bf(p0.w) << 16);
                va0.z = f2bf(p1.x) | (f2bf(p1.y) << 16); va0.w = f2bf(p1.z) | (f2bf(p1.w) << 16);
            }
            if (v1) {
                float4 p0 = *(const float4*)(a1pf + k0);
                float4 p1 = *(const float4*)(a1pf + k0 + 4);
                va1.x = f2bf(p0.x) | (f2bf(p0.y) << 16); va1.y = f2bf(p0.z) | (f2bf(p0.w) << 16);
                va1.z = f2bf(p1.x) | (f2bf(p1.y) << 16); va1.w = f2bf(p1.z) | (f2bf(p1.w) << 16);
            }
        } else {
            if (v0) va0 = *(const int4*)(a0p + k0);
            if (v1) va1 = *(const int4*)(a1p + k0);
        }
        int4 vw0 = *(const int4*)(w0p + k0);
        int4 vw1 = *(const int4*)(w1p + k0);
        __syncthreads();   // protect previous-iteration reads
        *(int4*)(As + wo0) = va0;
        *(int4*)(As + wo1) = va1;
        *(int4*)(Ws + wo0) = vw0;
        *(int4*)(Ws + wo1) = vw1;
        __syncthreads();
        #pragma unroll
        for (int ks = 0; ks < 2; ++ks) {
            int kb = ks*64;
            short8 a0 = *(const short8*)(As + ((baseA0 + kb) ^ swz));
            short8 a1 = *(const short8*)(As + ((baseA1 + kb) ^ swz));
            short8 b0 = *(const short8*)(Ws + ((baseB0 + kb) ^ swz));
            short8 b1 = *(const short8*)(Ws + ((baseB1 + kb) ^ swz));
            acc[0][0] = __builtin_amdgcn_mfma_f32_16x16x32_bf16(a0, b0, acc[0][0], 0, 0, 0);
            acc[0][1] = __builtin_amdgcn_mfma_f32_16x16x32_bf16(a0, b1, acc[0][1], 0, 0, 0);
            acc[1][0] = __builtin_amdgcn_mfma_f32_16x16x32_bf16(a1, b0, acc[1][0], 0, 0, 0);
            acc[1][1] = __builtin_amdgcn_mfma_f32_16x16x32_bf16(a1, b1, acc[1][1], 0, 0, 0);
        }
    }
    // epilogue: C/D layout col=lane&15, row=(lane>>4)*4+reg
    float bv0 = bias[bn + wn + lrow];
    float bv1 = bias[bn + wn + 16 + lrow];
    #pragma unroll
    for (int mi = 0; mi < 2; ++mi) {
        #pragma unroll
        for (int r = 0; r < 4; ++r) {
            int row = bm + wm + mi*16 + lq*4 + r;
            if (row >= M) continue;
            #pragma unroll
            for (int ni = 0; ni < 2; ++ni) {
                float v = acc[mi][ni][r] + (ni ? bv1 : bv0);
                if (ACT == 1) v = leaky(v);
                int col = bn + wn + ni*16 + lrow;
                if (RES)       Cres[(size_t)row*N + col] += v;
                else if (OUTF) Cres[(size_t)row*N + col] = v;
                else           Cbf[(size_t)row*N + col] = __float2bfloat16(v);
            }
        }
    }
}

// ---------------- neighborhood attention (bf16 in/out): one thread per (token, head) ----------------
__global__ __launch_bounds__(256) void attn_kernel(const __hip_bfloat16* __restrict__ qkv,
    const float* __restrict__ rpb, __hip_bfloat16* __restrict__ o)
{
    int gid = blockIdx.x*256 + threadIdx.x;
    int tok = gid >> 3;
    if (tok >= TOK) return;
    int head = gid & 7;
    int b = tok / (HF*WF);
    int rem = tok - b*HF*WF;
    int y = rem / WF, x = rem - y*WF;
    const ushort8* qp = (const ushort8*)(qkv + (size_t)tok*384 + head*16);
    float q[16];
    {
        ushort8 u0 = qp[0], u1 = qp[1];
        #pragma unroll
        for (int i = 0; i < 8; ++i) { q[i] = bf2f(u0[i])*0.25f; q[i+8] = bf2f(u1[i])*0.25f; }
    }
    float logits[25];
    float mx = -1e30f;
    #pragma unroll
    for (int di = -2; di <= 2; ++di) {
        int ny = y + di; ny += (ny < 0) ? HF : 0; ny -= (ny >= HF) ? HF : 0;
        #pragma unroll
        for (int dj = -2; dj <= 2; ++dj) {
            int nx = x + dj; nx += (nx < 0) ? WF : 0; nx -= (nx >= WF) ? WF : 0;
            size_t nt = (size_t)((b*HF + ny)*WF + nx);
            const ushort8* kp = (const ushort8*)(qkv + nt*384 + 128 + head*16);
            ushort8 k0 = kp[0], k1 = kp[1];
            float d = 0.f;
            #pragma unroll
            for (int i = 0; i < 8; ++i) d += q[i]*bf2f(k0[i]) + q[i+8]*bf2f(k1[i]);
            d += rpb[head*81 + (di+4)*9 + (dj+4)];
            logits[(di+2)*5 + (dj+2)] = d;
            mx = fmaxf(mx, d);
        }
    }
    float s = 0.f;
    #pragma unroll
    for (int n = 0; n < 25; ++n) { float p = __expf(logits[n]-mx); logits[n] = p; s += p; }
    float invs = 1.f/s;
    float outv[16] = {};
    #pragma unroll
    for (int di = -2; di <= 2; ++di) {
        int ny = y + di; ny += (ny < 0) ? HF : 0; ny -= (ny >= HF) ? HF : 0;
        #pragma unroll
        for (int dj = -2; dj <= 2; ++dj) {
            int nx = x + dj; nx += (nx < 0) ? WF : 0; nx -= (nx >= WF) ? WF : 0;
            size_t nt = (size_t)((b*HF + ny)*WF + nx);
            const ushort8* vp = (const ushort8*)(qkv + nt*384 + 256 + head*16);
            ushort8 v0 = vp[0], v1 = vp[1];
            float p = logits[(di+2)*5 + (dj+2)];
            #pragma unroll
            for (int i = 0; i < 8; ++i) { outv[i] += p*bf2f(v0[i]); outv[i+8] += p*bf2f(v1[i]); }
        }
    }
    __hip_bfloat16* op = o + (size_t)tok*DMOD + head*16;
    #pragma unroll
    for (int i = 0; i < 16; ++i) op[i] = __float2bfloat16(outv[i]*invs);
}

// ---------------- depatch gather: y[b,c,i,j] = db[c] + 4 taps of G ----------------
__global__ __launch_bounds__(256) void degather_kernel(const float* __restrict__ G,
    const float* __restrict__ db, float* __restrict__ yimg)
{
    int idx = blockIdx.x*256 + threadIdx.x;
    int b = idx >> 16;
    int pix = idx & 65535;
    int i = pix >> 8, j = pix & 255;
    int fh0 = i >> 1, fw0 = j >> 1;
    size_t r00 = ((size_t)(b*HF + fh0)*WF + fw0)*64;
    size_t r01 = r00 + 64;
    size_t r10 = r00 + (size_t)WF*64;
    size_t r11 = r10 + 64;
    int wr0 = (2 + (i & 1))*4, wr1 = (i & 1)*4;
    int wc0 = 2 + (j & 1), wc1 = (j & 1);
    #pragma unroll
    for (int c = 0; c < 3; ++c) {
        int e = c*16;
        float v = db[c]
                + G[r00 + e + wr0 + wc0] + G[r01 + e + wr0 + wc1]
                + G[r10 + e + wr1 + wc0] + G[r11 + e + wr1 + wc1];
        yimg[((size_t)(b*3 + c) << 16) + pix] = v;
    }
}

// ---------------- residual conv tail: out = y + conv1x1(leaky(conv5x5_wrap(y))) ----------------
__global__ __launch_bounds__(256) void res_kernel(const float* __restrict__ y,
    const float* __restrict__ w1, const float* __restrict__ b1,
    const float* __restrict__ w2, const float* __restrict__ b2, float* __restrict__ out)
{
    int idx = blockIdx.x*256 + threadIdx.x;
    int b = idx >> 16;
    int pix = idx & 65535;
    int i = pix >> 8, j = pix & 255;
    float yv[3][5][5];
    #pragma unroll
    for (int c = 0; c < 3; ++c) {
        #pragma unroll
        for (int u = 0; u < 5; ++u) {
            int ii = (i + u - 2 + 256) & 255;
            #pragma unroll
            for (int v = 0; v < 5; ++v) {
                int jj = (j + v - 2 + 256) & 255;
                yv[c][u][v] = y[((size_t)(b*3 + c)*256 + ii)*256 + jj];
            }
        }
    }
    float r1[12];
    #pragma unroll
    for (int rc = 0; rc < 12; ++rc) {
        float a = b1[rc];
        #pragma unroll
        for (int c = 0; c < 3; ++c)
            #pragma unroll
            for (int u = 0; u < 5; ++u)
                #pragma unroll
                for (int v = 0; v < 5; ++v)
                    a += yv[c][u][v] * w1[rc*75 + c*25 + u*5 + v];
        r1[rc] = leaky(a);
    }
    #pragma unroll
    for (int c = 0; c < 3; ++c) {
        float a = b2[c];
        #pragma unroll
        for (int rc = 0; rc < 12; ++rc) a += r1[rc]*w2[c*12 + rc];
        out[((size_t)(b*3 + c)*256 + i)*256 + j] = yv[c][2][2] + a;
    }
}

extern "C" void kernel_launch(void* const* d_in, const int* in_sizes, int n_in,
                              void* d_out, int out_size, void* d_ws, size_t ws_size,
                              hipStream_t stream)
{
    const float* x      = (const float*)d_in[0];
    const float* pos_w  = (const float*)d_in[1];
    const float* pos_b  = (const float*)d_in[2];
    const float* patch_w= (const float*)d_in[3];
    const float* patch_b= (const float*)d_in[4];
    const float* ln1_g  = (const float*)d_in[5];
    const float* ln1_b  = (const float*)d_in[6];
    const float* qkv_w  = (const float*)d_in[7];
    const float* qkv_b  = (const float*)d_in[8];
    const float* rpb    = (const float*)d_in[9];
    const float* proj_w = (const float*)d_in[10];
    const float* proj_b = (const float*)d_in[11];
    const float* ln2_g  = (const float*)d_in[12];
    const float* ln2_b  = (const float*)d_in[13];
    const float* fc1_w  = (const float*)d_in[14];
    const float* fc1_b  = (const float*)d_in[15];
    const float* fc2_w  = (const float*)d_in[16];
    const float* fc2_b  = (const float*)d_in[17];
    const float* dep_w  = (const float*)d_in[18];
    const float* dep_b  = (const float*)d_in[19];
    const float* rc1_w  = (const float*)d_in[20];
    const float* rc1_b  = (const float*)d_in[21];
    const float* rc2_w  = (const float*)d_in[22];
    const float* rc2_b  = (const float*)d_in[23];

    const size_t SZ = (size_t)TOK * 128;
    char* w = (char*)d_ws;
    float* f            = (float*)w;            w += SZ*4;
    __hip_bfloat16* yln = (__hip_bfloat16*)w;   w += SZ*2;
    __hip_bfloat16* qkvb= (__hip_bfloat16*)w;   w += (size_t)TOK*384*2;
    __hip_bfloat16* hb  = (__hip_bfloat16*)w;   w += (size_t)TOK*512*2;
    float* yimg         = (float*)w;            w += (size_t)BDIM*3*65536*4;
    __hip_bfloat16* wq  = (__hip_bfloat16*)w;   w += (size_t)NQ*2;
    __hip_bfloat16* wp  = (__hip_bfloat16*)w;   w += (size_t)NPJ*2;
    __hip_bfloat16* w1  = (__hip_bfloat16*)w;   w += (size_t)N1*2;
    __hip_bfloat16* w2  = (__hip_bfloat16*)w;   w += (size_t)N2*2;
    __hip_bfloat16* wpat= (__hip_bfloat16*)w;   w += (size_t)NPAT*2;
    __hip_bfloat16* wdep= (__hip_bfloat16*)w;   w += (size_t)NDEP*2;
    float* zero64       = (float*)w;            w += 64*4;

    // disjoint lifetimes: im2col output aliases qkvb, depatch G aliases hb
    __hip_bfloat16* icol = qkvb;   // TOK*64 bf16
    float* G             = (float*)hb;  // TOK*64 f32

    const int PREP_TOT = NQ + NPJ + N1 + N2 + NPAT + NDEP + 64;
    prep_weights<<<(PREP_TOT + 255)/256, 256, 0, stream>>>(
        qkv_w, proj_w, fc1_w, fc2_w, patch_w, dep_w, wq, wp, w1, w2, wpat, wdep, zero64);

    im2col_kernel<<<BDIM*HF, 256, 0, stream>>>(x, pos_w, pos_b, icol);

    const int GM = (TOK + 63)/64;   // 521
    // patchify GEMM: [T,64] @ wpat[128,64]^T -> f (f32)
    mgemm_kernel<0,0,1,0><<<dim3(GM,2), 256, 0, stream>>>(icol, wpat, patch_b,
        nullptr, f, TOK, 128, 64);

    for (int l = 0; l < 3; ++l) {
        ln_kernel<<<(TOK+3)/4, 256, 0, stream>>>(f, ln1_g + l*128, ln1_b + l*128, yln);
        mgemm_kernel<0,0,0,0><<<dim3(GM,6), 256, 0, stream>>>(yln, wq + (size_t)l*384*128,
            qkv_b + l*384, qkvb, nullptr, TOK, 384, 128);
        attn_kernel<<<(TOK*8 + 255)/256, 256, 0, stream>>>(qkvb, rpb + l*8*81, yln);
        mgemm_kernel<0,1,0,0><<<dim3(GM,2), 256, 0, stream>>>(yln, wp + (size_t)l*128*128,
            proj_b + l*128, nullptr, f, TOK, 128, 128);
        ln_kernel<<<(TOK+3)/4, 256, 0, stream>>>(f, ln2_g + l*128, ln2_b + l*128, yln);
        mgemm_kernel<1,0,0,0><<<dim3(GM,8), 256, 0, stream>>>(yln, w1 + (size_t)l*512*128,
            fc1_b + l*512, hb, nullptr, TOK, 512, 128);
        mgemm_kernel<0,1,0,0><<<dim3(GM,2), 256, 0, stream>>>(hb, w2 + (size_t)l*128*512,
            fc2_b + l*128, nullptr, f, TOK, 128, 512);
    }

    // depatchify: G[T,64] = f[T,128] @ wdep[64,128]^T  (cols 48..63 are zero)
    mgemm_kernel<0,0,1,1><<<dim3(GM,1), 256, 0, stream>>>(f, wdep, zero64,
        nullptr, G, TOK, 64, 128);
    degather_kernel<<<512, 256, 0, stream>>>(G, dep_b, yimg);

    res_kernel<<<512, 256, 0, stream>>>(yimg, rc1_w, rc1_b, rc2_w, rc2_b, (float*)d_out);
}